// Round 2
// baseline (268.356 us; speedup 1.0000x reference)
//
#include <hip/hip_runtime.h>

// Batch-as-N MFMA mapping: Y^T[j,b] = W^T[j,k] @ H^T[k,b] via mfma_f32_16x16x32_bf16.
// b (batch row within 16-tile) lives in lane&15 for the ENTIRE network:
//   B-frag (activations): lane holds n=lane&15, k = quad*8 + 0..7   (quad = lane>>4)
//   D      (outputs):     lane holds n=lane&15, j = t*16 + quad*4 + reg
// Layer1 (2->32) computes its 8 outputs directly in B-frag layout (no shuffle).
// Layer3 (32->{2,1}) is per-lane partials over the lane's 8 j-values + quad-reduce
// via v_permlane16/32_swap (VALU, no DS latency).
//
// R1 changes vs 53us/dispatch baseline (resubmitted R2 — R1 hit GPUAcquisitionTimeout):
//  - launch_bounds(256,8): VGPR<=64 (was 68, just over the 64-reg occupancy cliff)
//  - grid 768 -> 2048 blocks: 8 blocks/CU, 32 waves/CU target (was 12)
//  - 2*log2(e) folded into layer-1/2 weights+biases at preload: tanh = exp2,rcp,fma only
//  - layer-2 bias folded into MFMA C operand (saves 16 adds/iter)
//  - bf16 packing via plain casts -> compiler emits v_cvt_pk_bf16_f32 (saves 16 ops/iter)
//  - __shfl_xor(16/32) -> v_permlane16_swap/v_permlane32_swap butterfly (kills lgkmcnt chain)

typedef __bf16 bf16x8 __attribute__((ext_vector_type(8)));
typedef float f32x4 __attribute__((ext_vector_type(4)));

#define KTANH 2.8853900817779268f  // 2*log2(e), folded into pre-activation scale

__device__ __forceinline__ float tanh_pre(float z) {
    // input already scaled by KTANH: tanh = 1 - 2/(exp2(z)+1); saturates correctly at +-inf
    float e = __builtin_amdgcn_exp2f(z);
    float r = __builtin_amdgcn_rcpf(e + 1.0f);
    return __builtin_fmaf(-2.0f, r, 1.0f);
}

__device__ __forceinline__ float quad_sum(float v) {
    // sum over the 4 quads (lanes l, l^16, l^32, l^48) using full-rate VALU lane swaps.
    // For a pairwise swap instr, out_a + out_b == v[l] + v[l^stage] regardless of convention.
    float a = v, b = v;
    asm("v_permlane16_swap_b32 %0, %1" : "+v"(a), "+v"(b));
    float s = a + b;
    float c = s, d = s;
    asm("v_permlane32_swap_b32 %0, %1" : "+v"(c), "+v"(d));
    return c + d;
}

__global__ __launch_bounds__(256, 8) void damping_mfma(
    const float* __restrict__ x,
    const float* __restrict__ w_d1, const float* __restrict__ w_d2, const float* __restrict__ w_d3,
    const float* __restrict__ w_o1, const float* __restrict__ w_o2, const float* __restrict__ w_o3,
    const float* __restrict__ b_d1, const float* __restrict__ b_d2, const float* __restrict__ b_d3,
    const float* __restrict__ b_o1, const float* __restrict__ b_o2, const float* __restrict__ b_o3,
    float* __restrict__ out, int n_tiles)
{
    const int lane = threadIdx.x & 63;
    const int quad = lane >> 4;
    const int b16  = lane & 15;
    const int wid     = (int)((blockIdx.x * blockDim.x + threadIdx.x) >> 6);
    const int n_waves = (int)((gridDim.x * blockDim.x) >> 6);

    // ---------------- per-lane constant preload (once per wave) ----------------
    // Layer1 weights in B-frag k-order: k = quad*8 + j.  Pre-scaled by KTANH.
    float w1d0[8], w1d1[8], bd1[8], w1o0[8], w1o1[8], bo1[8];
    #pragma unroll
    for (int j = 0; j < 8; ++j) {
        int k = quad * 8 + j;
        w1d0[j] = w_d1[k] * KTANH; w1d1[j] = w_d1[32 + k] * KTANH; bd1[j] = b_d1[k] * KTANH;
        w1o0[j] = w_o1[k] * KTANH; w1o1[j] = w_o1[32 + k] * KTANH; bo1[j] = b_o1[k] * KTANH;
    }
    // Layer2 A-frags (pre-scaled): A[m][k] = KTANH*W^T[j=t*16+m][k]; m=b16, k=quad*8+j
    bf16x8 a_d2[2], a_o2[2];
    #pragma unroll
    for (int t = 0; t < 2; ++t) {
        #pragma unroll
        for (int j = 0; j < 8; ++j) {
            int k = quad * 8 + j;
            a_d2[t][j] = (__bf16)(w_d2[k * 32 + t * 16 + b16] * KTANH);
            a_o2[t][j] = (__bf16)(w_o2[k * 32 + t * 16 + b16] * KTANH);
        }
    }
    // Layer2 bias as MFMA C operand: reg i of tile t holds j = t*16 + quad*4 + i (pre-scaled)
    f32x4 cd[2], co[2];
    #pragma unroll
    for (int t = 0; t < 2; ++t) {
        #pragma unroll
        for (int i = 0; i < 4; ++i) {
            int jj = t * 16 + quad * 4 + i;
            cd[t][i] = b_d2[jj] * KTANH;
            co[t][i] = b_o2[jj] * KTANH;
        }
    }
    // Layer3 weights at this lane's 8 j-values: j = (i>>2)*16 + quad*4 + (i&3)  (unscaled)
    float w3d0[8], w3d1[8], w3o[8];
    #pragma unroll
    for (int i = 0; i < 8; ++i) {
        int jj = (i >> 2) * 16 + quad * 4 + (i & 3);
        w3d0[i] = w_d3[jj * 2]; w3d1[i] = w_d3[jj * 2 + 1];
        w3o[i]  = w_o3[jj];
    }
    const float bd3_0 = b_d3[0], bd3_1 = b_d3[1], bo3_0 = b_o3[0];

    const float2* x2 = (const float2*)x;
    int tile = wid;
    if (tile >= n_tiles) return;
    float2 xv = x2[tile * 16 + b16];

    for (; tile < n_tiles; tile += n_waves) {
        // software prefetch next tile's x (clamped; hides VMEM latency behind compute)
        int nt = tile + n_waves;
        nt = (nt < n_tiles) ? nt : tile;
        float2 xnext = x2[nt * 16 + b16];

        const float x0 = xv.x, x1 = xv.y;

        // -------- layer 1 (both branches), directly in B-frag layout --------
        float hd[8], ho[8];
        #pragma unroll
        for (int j = 0; j < 8; ++j) {
            hd[j] = tanh_pre(fmaf(x1, w1d1[j], fmaf(x0, w1d0[j], bd1[j])));
            ho[j] = tanh_pre(fmaf(x1, w1o1[j], fmaf(x0, w1o0[j], bo1[j])));
        }
        bf16x8 bfd, bfo;
        #pragma unroll
        for (int j = 0; j < 8; ++j) {
            bfd[j] = (__bf16)hd[j];   // compiler pairs these into v_cvt_pk_bf16_f32
            bfo[j] = (__bf16)ho[j];
        }

        // -------- layer 2: 4 independent MFMAs (2 j-tiles x 2 branches), bias in C --------
        f32x4 d0 = __builtin_amdgcn_mfma_f32_16x16x32_bf16(a_d2[0], bfd, cd[0], 0, 0, 0);
        f32x4 d1 = __builtin_amdgcn_mfma_f32_16x16x32_bf16(a_d2[1], bfd, cd[1], 0, 0, 0);
        f32x4 o0 = __builtin_amdgcn_mfma_f32_16x16x32_bf16(a_o2[0], bfo, co[0], 0, 0, 0);
        f32x4 o1 = __builtin_amdgcn_mfma_f32_16x16x32_bf16(a_o2[1], bfo, co[1], 0, 0, 0);

        // -------- layer 2 act + layer 3 partials --------
        float pd0 = 0.f, pd1 = 0.f, po = 0.f;
        #pragma unroll
        for (int i = 0; i < 8; ++i) {
            float h2d = tanh_pre(i < 4 ? d0[i] : d1[i - 4]);
            float h2o = tanh_pre(i < 4 ? o0[i] : o1[i - 4]);
            pd0 = fmaf(h2d, w3d0[i], pd0);
            pd1 = fmaf(h2d, w3d1[i], pd1);
            po  = fmaf(h2o, w3o[i], po);
        }
        // reduce across the 4 quads (same b16) -- pure VALU, no DS waits
        pd0 = quad_sum(pd0);
        pd1 = quad_sum(pd1);
        po  = quad_sum(po);

        // -------- epilogue --------
        float d30 = pd0 + bd3_0, d31 = pd1 + bd3_1, c = po + bo3_0;
        float a = (fmaxf(d30, 0.f) + 0.001f) * x0;
        float b = (fmaxf(d31, 0.f) + 0.001f) * x1;
        float D0 = fmaf(a * a, x0, a * c * x1);
        float D1 = fmaf(a * c, x0, fmaf(c, c, b * b) * x1);

        if (quad == 0) ((float2*)out)[tile * 16 + b16] = make_float2(D0, D1);
        xv = xnext;
    }
}

extern "C" void kernel_launch(void* const* d_in, const int* in_sizes, int n_in,
                              void* d_out, int out_size, void* d_ws, size_t ws_size,
                              hipStream_t stream) {
    const float* x    = (const float*)d_in[0];
    const float* w_d1 = (const float*)d_in[1];
    const float* w_d2 = (const float*)d_in[2];
    const float* w_d3 = (const float*)d_in[3];
    const float* w_o1 = (const float*)d_in[4];
    const float* w_o2 = (const float*)d_in[5];
    const float* w_o3 = (const float*)d_in[6];
    const float* b_d1 = (const float*)d_in[7];
    const float* b_d2 = (const float*)d_in[8];
    const float* b_d3 = (const float*)d_in[9];
    const float* b_o1 = (const float*)d_in[10];
    const float* b_o2 = (const float*)d_in[11];
    const float* b_o3 = (const float*)d_in[12];
    float* out = (float*)d_out;

    int n = in_sizes[0] / 2;         // rows
    int n_tiles = n / 16;            // 16 rows per wave-iteration
    // 2048 blocks * 4 waves = 8192 waves -> 8 blocks/CU, 32 waves/CU at launch_bounds(256,8)
    int blocks_needed = (n_tiles + 3) / 4;
    int grid = blocks_needed < 2048 ? blocks_needed : 2048;
    damping_mfma<<<grid, 256, 0, stream>>>(
        x, w_d1, w_d2, w_d3, w_o1, w_o2, w_o3,
        b_d1, b_d2, b_d3, b_o1, b_o2, b_o3, out, n_tiles);
}

// Round 6
// 125.670 us; speedup vs baseline: 2.1354x; 2.1354x over previous
//
#include <hip/hip_runtime.h>

// Batch-as-N MFMA mapping: Y^T[j,b] = W^T[j,k] @ H^T[k,b] via mfma_f32_16x16x32_bf16.
// b (batch row within 16-tile) lives in lane&15 for the ENTIRE network:
//   B-frag (activations): lane holds n=lane&15, k = quad*8 + 0..7   (quad = lane>>4)
//   D      (outputs):     lane holds n=lane&15, j = t*16 + quad*4 + reg
// Layer1 (2->32) computes its 8 outputs directly in B-frag layout (no shuffle).
// Layer3 (32->{2,1}) is per-lane partials over the lane's 8 j-values + quad-reduce
// via __shfl_xor(16/32) (proven correct in baseline and R2).
//
// Session ledger:
//  - R2 (passed): KTANH fold + bias-in-C + cast packing validated correct; but
//    launch_bounds(256,8) forced VGPR=32 -> ~107-float constant set spilled to
//    scratch (FETCH 4MB->600MB, 197us). 64-VGPR tier unreachable for this kernel.
//  - R3/R4 (failed): permlane16/32_swap with BOTH operands fed the same value is a
//    register-coalescing hazard (asm AND builtin) -> wrong reduce under the
//    launch_bounds(256,4) allocation. Permlane abandoned; shfl_xor restored.
//  - R5: GPUAcquisitionTimeout (infra). This is an identical resubmission.
// R6 = R1 VALU cuts + launch_bounds(256,4) (VGPR cap 128, fits ~107 constants +
//      temps, no spill) + grid 1024 blocks = 4096 waves = 16 waves/CU
//      (baseline grid gave only 12), 16 tiles/wave perfectly balanced.

typedef __bf16 bf16x8 __attribute__((ext_vector_type(8)));
typedef float f32x4 __attribute__((ext_vector_type(4)));

#define KTANH 2.8853900817779268f  // 2*log2(e), folded into pre-activation scale

__device__ __forceinline__ float tanh_pre(float z) {
    // input already scaled by KTANH: tanh = 1 - 2/(exp2(z)+1); saturates correctly at +-inf
    float e = __builtin_amdgcn_exp2f(z);
    float r = __builtin_amdgcn_rcpf(e + 1.0f);
    return __builtin_fmaf(-2.0f, r, 1.0f);
}

__device__ __forceinline__ float quad_sum(float v) {
    // sum over the 4 quads (lanes l, l^16, l^32, l^48) -- proven-correct shuffle path
    v += __shfl_xor(v, 16);
    v += __shfl_xor(v, 32);
    return v;
}

__global__ __launch_bounds__(256, 4) void damping_mfma(
    const float* __restrict__ x,
    const float* __restrict__ w_d1, const float* __restrict__ w_d2, const float* __restrict__ w_d3,
    const float* __restrict__ w_o1, const float* __restrict__ w_o2, const float* __restrict__ w_o3,
    const float* __restrict__ b_d1, const float* __restrict__ b_d2, const float* __restrict__ b_d3,
    const float* __restrict__ b_o1, const float* __restrict__ b_o2, const float* __restrict__ b_o3,
    float* __restrict__ out, int n_tiles)
{
    const int lane = threadIdx.x & 63;
    const int quad = lane >> 4;
    const int b16  = lane & 15;
    const int wid     = (int)((blockIdx.x * blockDim.x + threadIdx.x) >> 6);
    const int n_waves = (int)((gridDim.x * blockDim.x) >> 6);

    // ---------------- per-lane constant preload (once per wave) ----------------
    // Layer1 weights in B-frag k-order: k = quad*8 + j.  Pre-scaled by KTANH.
    float w1d0[8], w1d1[8], bd1[8], w1o0[8], w1o1[8], bo1[8];
    #pragma unroll
    for (int j = 0; j < 8; ++j) {
        int k = quad * 8 + j;
        w1d0[j] = w_d1[k] * KTANH; w1d1[j] = w_d1[32 + k] * KTANH; bd1[j] = b_d1[k] * KTANH;
        w1o0[j] = w_o1[k] * KTANH; w1o1[j] = w_o1[32 + k] * KTANH; bo1[j] = b_o1[k] * KTANH;
    }
    // Layer2 A-frags (pre-scaled): A[m][k] = KTANH*W^T[j=t*16+m][k]; m=b16, k=quad*8+j
    bf16x8 a_d2[2], a_o2[2];
    #pragma unroll
    for (int t = 0; t < 2; ++t) {
        #pragma unroll
        for (int j = 0; j < 8; ++j) {
            int k = quad * 8 + j;
            a_d2[t][j] = (__bf16)(w_d2[k * 32 + t * 16 + b16] * KTANH);
            a_o2[t][j] = (__bf16)(w_o2[k * 32 + t * 16 + b16] * KTANH);
        }
    }
    // Layer2 bias as MFMA C operand: reg i of tile t holds j = t*16 + quad*4 + i (pre-scaled)
    f32x4 cd[2], co[2];
    #pragma unroll
    for (int t = 0; t < 2; ++t) {
        #pragma unroll
        for (int i = 0; i < 4; ++i) {
            int jj = t * 16 + quad * 4 + i;
            cd[t][i] = b_d2[jj] * KTANH;
            co[t][i] = b_o2[jj] * KTANH;
        }
    }
    // Layer3 weights at this lane's 8 j-values: j = (i>>2)*16 + quad*4 + (i&3)  (unscaled)
    float w3d0[8], w3d1[8], w3o[8];
    #pragma unroll
    for (int i = 0; i < 8; ++i) {
        int jj = (i >> 2) * 16 + quad * 4 + (i & 3);
        w3d0[i] = w_d3[jj * 2]; w3d1[i] = w_d3[jj * 2 + 1];
        w3o[i]  = w_o3[jj];
    }
    const float bd3_0 = b_d3[0], bd3_1 = b_d3[1], bo3_0 = b_o3[0];

    const float2* x2 = (const float2*)x;
    int tile = wid;
    if (tile >= n_tiles) return;
    float2 xv = x2[tile * 16 + b16];

    for (; tile < n_tiles; tile += n_waves) {
        // software prefetch next tile's x (clamped; hides VMEM latency behind compute)
        int nt = tile + n_waves;
        nt = (nt < n_tiles) ? nt : tile;
        float2 xnext = x2[nt * 16 + b16];

        const float x0 = xv.x, x1 = xv.y;

        // -------- layer 1 (both branches), directly in B-frag layout --------
        float hd[8], ho[8];
        #pragma unroll
        for (int j = 0; j < 8; ++j) {
            hd[j] = tanh_pre(fmaf(x1, w1d1[j], fmaf(x0, w1d0[j], bd1[j])));
            ho[j] = tanh_pre(fmaf(x1, w1o1[j], fmaf(x0, w1o0[j], bo1[j])));
        }
        bf16x8 bfd, bfo;
        #pragma unroll
        for (int j = 0; j < 8; ++j) {
            bfd[j] = (__bf16)hd[j];   // compiler pairs these into v_cvt_pk_bf16_f32
            bfo[j] = (__bf16)ho[j];
        }

        // -------- layer 2: 4 independent MFMAs (2 j-tiles x 2 branches), bias in C --------
        f32x4 d0 = __builtin_amdgcn_mfma_f32_16x16x32_bf16(a_d2[0], bfd, cd[0], 0, 0, 0);
        f32x4 d1 = __builtin_amdgcn_mfma_f32_16x16x32_bf16(a_d2[1], bfd, cd[1], 0, 0, 0);
        f32x4 o0 = __builtin_amdgcn_mfma_f32_16x16x32_bf16(a_o2[0], bfo, co[0], 0, 0, 0);
        f32x4 o1 = __builtin_amdgcn_mfma_f32_16x16x32_bf16(a_o2[1], bfo, co[1], 0, 0, 0);

        // -------- layer 2 act + layer 3 partials --------
        float pd0 = 0.f, pd1 = 0.f, po = 0.f;
        #pragma unroll
        for (int i = 0; i < 8; ++i) {
            float h2d = tanh_pre(i < 4 ? d0[i] : d1[i - 4]);
            float h2o = tanh_pre(i < 4 ? o0[i] : o1[i - 4]);
            pd0 = fmaf(h2d, w3d0[i], pd0);
            pd1 = fmaf(h2d, w3d1[i], pd1);
            po  = fmaf(h2o, w3o[i], po);
        }
        // reduce across the 4 quads (same b16)
        pd0 = quad_sum(pd0);
        pd1 = quad_sum(pd1);
        po  = quad_sum(po);

        // -------- epilogue --------
        float d30 = pd0 + bd3_0, d31 = pd1 + bd3_1, c = po + bo3_0;
        float a = (fmaxf(d30, 0.f) + 0.001f) * x0;
        float b = (fmaxf(d31, 0.f) + 0.001f) * x1;
        float D0 = fmaf(a * a, x0, a * c * x1);
        float D1 = fmaf(a * c, x0, fmaf(c, c, b * b) * x1);

        if (quad == 0) ((float2*)out)[tile * 16 + b16] = make_float2(D0, D1);
        xv = xnext;
    }
}

extern "C" void kernel_launch(void* const* d_in, const int* in_sizes, int n_in,
                              void* d_out, int out_size, void* d_ws, size_t ws_size,
                              hipStream_t stream) {
    const float* x    = (const float*)d_in[0];
    const float* w_d1 = (const float*)d_in[1];
    const float* w_d2 = (const float*)d_in[2];
    const float* w_d3 = (const float*)d_in[3];
    const float* w_o1 = (const float*)d_in[4];
    const float* w_o2 = (const float*)d_in[5];
    const float* w_o3 = (const float*)d_in[6];
    const float* b_d1 = (const float*)d_in[7];
    const float* b_d2 = (const float*)d_in[8];
    const float* b_d3 = (const float*)d_in[9];
    const float* b_o1 = (const float*)d_in[10];
    const float* b_o2 = (const float*)d_in[11];
    const float* b_o3 = (const float*)d_in[12];
    float* out = (float*)d_out;

    int n = in_sizes[0] / 2;         // rows
    int n_tiles = n / 16;            // 16 rows per wave-iteration
    // 1024 blocks * 4 waves = 4096 waves = 16 waves/CU = 4 waves/SIMD:
    // exactly fills the VGPR (64,128] occupancy tier under launch_bounds(256,4).
    // 65536 tiles / 4096 waves = 16 iterations per wave, perfectly balanced.
    int blocks_needed = (n_tiles + 3) / 4;
    int grid = blocks_needed < 1024 ? blocks_needed : 1024;
    damping_mfma<<<grid, 256, 0, stream>>>(
        x, w_d1, w_d2, w_d3, w_o1, w_o2, w_o3,
        b_d1, b_d2, b_d3, b_o1, b_o2, b_o3, out, n_tiles);
}

// Round 7
// 121.404 us; speedup vs baseline: 2.2104x; 1.0351x over previous
//
#include <hip/hip_runtime.h>

// Batch-as-N MFMA mapping: Y^T[j,b] = W^T[j,k] @ H^T[k,b] via mfma_f32_16x16x32_bf16.
// b (batch row within 16-tile) lives in lane&15 for the ENTIRE network:
//   B-frag (activations): lane holds n=lane&15, k = quad*8 + 0..7   (quad = lane>>4)
//   D      (outputs):     lane holds n=lane&15, j = t*16 + quad*4 + reg
// Layer1 (2->32) computes its 8 outputs directly in B-frag layout (no shuffle).
// Layer3 (32->{2,1}) is per-lane partials over the lane's 8 j-values + quad-reduce
// via __shfl_xor(16/32) (proven correct in baseline and R2/R6).
//
// Session ledger:
//  - R2 (passed, 197us): VALU cuts (KTANH fold + bias-in-C + cast packing) are
//    numerically validated; launch_bounds(256,8) -> VGPR=32, massive spill.
//  - R3/R4 (failed): permlane swap with both operands = same value is a regalloc
//    coalescing hazard. Abandoned; shfl_xor restored.
//  - R6 (passed, 53us = baseline): launch_bounds(256,4) -> VGPR=64 + spill
//    (WRITE 8->21.5MB, FETCH 4->9MB). Pattern: with MFMA present the forced
//    budget splits arch/acc, so (256,8)->32, (256,4)->64 usable arch VGPRs;
//    both below the ~70-reg live set. Only (256,3) allocates clean (68, baseline).
//    Spill stalls canceled the VALU-op savings (VALUBusy 67->56).
// R7 = R6 with launch_bounds(256,3) (single-variable change: clean allocation),
//      grid 1024 blocks = 16 waves/CU nominal at the 4-waves/SIMD tier (VGPR<=128).

typedef __bf16 bf16x8 __attribute__((ext_vector_type(8)));
typedef float f32x4 __attribute__((ext_vector_type(4)));

#define KTANH 2.8853900817779268f  // 2*log2(e), folded into pre-activation scale

__device__ __forceinline__ float tanh_pre(float z) {
    // input already scaled by KTANH: tanh = 1 - 2/(exp2(z)+1); saturates correctly at +-inf
    float e = __builtin_amdgcn_exp2f(z);
    float r = __builtin_amdgcn_rcpf(e + 1.0f);
    return __builtin_fmaf(-2.0f, r, 1.0f);
}

__device__ __forceinline__ float quad_sum(float v) {
    // sum over the 4 quads (lanes l, l^16, l^32, l^48) -- proven-correct shuffle path
    v += __shfl_xor(v, 16);
    v += __shfl_xor(v, 32);
    return v;
}

__global__ __launch_bounds__(256, 3) void damping_mfma(
    const float* __restrict__ x,
    const float* __restrict__ w_d1, const float* __restrict__ w_d2, const float* __restrict__ w_d3,
    const float* __restrict__ w_o1, const float* __restrict__ w_o2, const float* __restrict__ w_o3,
    const float* __restrict__ b_d1, const float* __restrict__ b_d2, const float* __restrict__ b_d3,
    const float* __restrict__ b_o1, const float* __restrict__ b_o2, const float* __restrict__ b_o3,
    float* __restrict__ out, int n_tiles)
{
    const int lane = threadIdx.x & 63;
    const int quad = lane >> 4;
    const int b16  = lane & 15;
    const int wid     = (int)((blockIdx.x * blockDim.x + threadIdx.x) >> 6);
    const int n_waves = (int)((gridDim.x * blockDim.x) >> 6);

    // ---------------- per-lane constant preload (once per wave) ----------------
    // Layer1 weights in B-frag k-order: k = quad*8 + j.  Pre-scaled by KTANH.
    float w1d0[8], w1d1[8], bd1[8], w1o0[8], w1o1[8], bo1[8];
    #pragma unroll
    for (int j = 0; j < 8; ++j) {
        int k = quad * 8 + j;
        w1d0[j] = w_d1[k] * KTANH; w1d1[j] = w_d1[32 + k] * KTANH; bd1[j] = b_d1[k] * KTANH;
        w1o0[j] = w_o1[k] * KTANH; w1o1[j] = w_o1[32 + k] * KTANH; bo1[j] = b_o1[k] * KTANH;
    }
    // Layer2 A-frags (pre-scaled): A[m][k] = KTANH*W^T[j=t*16+m][k]; m=b16, k=quad*8+j
    bf16x8 a_d2[2], a_o2[2];
    #pragma unroll
    for (int t = 0; t < 2; ++t) {
        #pragma unroll
        for (int j = 0; j < 8; ++j) {
            int k = quad * 8 + j;
            a_d2[t][j] = (__bf16)(w_d2[k * 32 + t * 16 + b16] * KTANH);
            a_o2[t][j] = (__bf16)(w_o2[k * 32 + t * 16 + b16] * KTANH);
        }
    }
    // Layer2 bias as MFMA C operand: reg i of tile t holds j = t*16 + quad*4 + i (pre-scaled)
    f32x4 cd[2], co[2];
    #pragma unroll
    for (int t = 0; t < 2; ++t) {
        #pragma unroll
        for (int i = 0; i < 4; ++i) {
            int jj = t * 16 + quad * 4 + i;
            cd[t][i] = b_d2[jj] * KTANH;
            co[t][i] = b_o2[jj] * KTANH;
        }
    }
    // Layer3 weights at this lane's 8 j-values: j = (i>>2)*16 + quad*4 + (i&3)  (unscaled)
    float w3d0[8], w3d1[8], w3o[8];
    #pragma unroll
    for (int i = 0; i < 8; ++i) {
        int jj = (i >> 2) * 16 + quad * 4 + (i & 3);
        w3d0[i] = w_d3[jj * 2]; w3d1[i] = w_d3[jj * 2 + 1];
        w3o[i]  = w_o3[jj];
    }
    const float bd3_0 = b_d3[0], bd3_1 = b_d3[1], bo3_0 = b_o3[0];

    const float2* x2 = (const float2*)x;
    int tile = wid;
    if (tile >= n_tiles) return;
    float2 xv = x2[tile * 16 + b16];

    for (; tile < n_tiles; tile += n_waves) {
        // software prefetch next tile's x (clamped; hides VMEM latency behind compute)
        int nt = tile + n_waves;
        nt = (nt < n_tiles) ? nt : tile;
        float2 xnext = x2[nt * 16 + b16];

        const float x0 = xv.x, x1 = xv.y;

        // -------- layer 1 (both branches), directly in B-frag layout --------
        float hd[8], ho[8];
        #pragma unroll
        for (int j = 0; j < 8; ++j) {
            hd[j] = tanh_pre(fmaf(x1, w1d1[j], fmaf(x0, w1d0[j], bd1[j])));
            ho[j] = tanh_pre(fmaf(x1, w1o1[j], fmaf(x0, w1o0[j], bo1[j])));
        }
        bf16x8 bfd, bfo;
        #pragma unroll
        for (int j = 0; j < 8; ++j) {
            bfd[j] = (__bf16)hd[j];   // compiler pairs these into v_cvt_pk_bf16_f32
            bfo[j] = (__bf16)ho[j];
        }

        // -------- layer 2: 4 independent MFMAs (2 j-tiles x 2 branches), bias in C --------
        f32x4 d0 = __builtin_amdgcn_mfma_f32_16x16x32_bf16(a_d2[0], bfd, cd[0], 0, 0, 0);
        f32x4 d1 = __builtin_amdgcn_mfma_f32_16x16x32_bf16(a_d2[1], bfd, cd[1], 0, 0, 0);
        f32x4 o0 = __builtin_amdgcn_mfma_f32_16x16x32_bf16(a_o2[0], bfo, co[0], 0, 0, 0);
        f32x4 o1 = __builtin_amdgcn_mfma_f32_16x16x32_bf16(a_o2[1], bfo, co[1], 0, 0, 0);

        // -------- layer 2 act + layer 3 partials --------
        float pd0 = 0.f, pd1 = 0.f, po = 0.f;
        #pragma unroll
        for (int i = 0; i < 8; ++i) {
            float h2d = tanh_pre(i < 4 ? d0[i] : d1[i - 4]);
            float h2o = tanh_pre(i < 4 ? o0[i] : o1[i - 4]);
            pd0 = fmaf(h2d, w3d0[i], pd0);
            pd1 = fmaf(h2d, w3d1[i], pd1);
            po  = fmaf(h2o, w3o[i], po);
        }
        // reduce across the 4 quads (same b16)
        pd0 = quad_sum(pd0);
        pd1 = quad_sum(pd1);
        po  = quad_sum(po);

        // -------- epilogue --------
        float d30 = pd0 + bd3_0, d31 = pd1 + bd3_1, c = po + bo3_0;
        float a = (fmaxf(d30, 0.f) + 0.001f) * x0;
        float b = (fmaxf(d31, 0.f) + 0.001f) * x1;
        float D0 = fmaf(a * a, x0, a * c * x1);
        float D1 = fmaf(a * c, x0, fmaf(c, c, b * b) * x1);

        if (quad == 0) ((float2*)out)[tile * 16 + b16] = make_float2(D0, D1);
        xv = xnext;
    }
}

extern "C" void kernel_launch(void* const* d_in, const int* in_sizes, int n_in,
                              void* d_out, int out_size, void* d_ws, size_t ws_size,
                              hipStream_t stream) {
    const float* x    = (const float*)d_in[0];
    const float* w_d1 = (const float*)d_in[1];
    const float* w_d2 = (const float*)d_in[2];
    const float* w_d3 = (const float*)d_in[3];
    const float* w_o1 = (const float*)d_in[4];
    const float* w_o2 = (const float*)d_in[5];
    const float* w_o3 = (const float*)d_in[6];
    const float* b_d1 = (const float*)d_in[7];
    const float* b_d2 = (const float*)d_in[8];
    const float* b_d3 = (const float*)d_in[9];
    const float* b_o1 = (const float*)d_in[10];
    const float* b_o2 = (const float*)d_in[11];
    const float* b_o3 = (const float*)d_in[12];
    float* out = (float*)d_out;

    int n = in_sizes[0] / 2;         // rows
    int n_tiles = n / 16;            // 16 rows per wave-iteration
    // 1024 blocks * 4 waves = 4096 waves: at ~68 VGPR (4 waves/SIMD tier) this is
    // 4 blocks/CU = 16 waves/CU nominal (baseline's 768-block grid gave only 12).
    // 65536 tiles / 4096 waves = 16 iterations per wave, perfectly balanced.
    int blocks_needed = (n_tiles + 3) / 4;
    int grid = blocks_needed < 1024 ? blocks_needed : 1024;
    damping_mfma<<<grid, 256, 0, stream>>>(
        x, w_d1, w_d2, w_d3, w_o1, w_o2, w_o3,
        b_d1, b_d2, b_d3, b_o1, b_o2, b_o3, out, n_tiles);
}

// Round 8
// 121.061 us; speedup vs baseline: 2.2167x; 1.0028x over previous
//
#include <hip/hip_runtime.h>

// Batch-as-N MFMA mapping: Y^T[j,b] = W^T[j,k] @ H^T[k,b] via mfma_f32_16x16x32_bf16.
// b (batch row within 16-tile) lives in lane&15 for the ENTIRE network:
//   B-frag (activations): lane holds n=lane&15, k = quad*8 + 0..7   (quad = lane>>4)
//   D      (outputs):     lane holds n=lane&15, j = t*16 + quad*4 + reg
// Layer1 (2->32) computes its 8 outputs directly in B-frag layout (no shuffle).
// Layer3 (32->{2,1}) is per-lane partials over the lane's 8 j-values + quad-reduce
// via __shfl_xor(16/32) (proven correct in baseline and R2/R6/R7).
//
// Session ledger:
//  - R2 (passed, 197us): VALU cuts validated numerically; launch_bounds(256,8)
//    -> VGPR=32, massive spill (FETCH 600MB).
//  - R3/R4 (failed): permlane swap w/ both operands same value = regalloc hazard.
//  - R6 (passed, 53us): launch_bounds(256,4) -> VGPR=64, mild spill canceled gains.
//  - R7 (passed, 47us): launch_bounds(256,3) clean @ VGPR=76, grid 1024.
//    FETCH/WRITE clean. VALUBusy 63. Issue floor ~22us -> still latency-limited.
//  - R8 (this): VGPR=76 rounds to 80 -> HW allows 6 waves/SIMD (512/80), but grid
//    1024 = only 4 blocks/CU. Single change: grid -> 1536 (6 blocks/CU) to fill
//    the VGPR-allowed residency. Predicted 47 -> ~38-42us, VALUBusy -> ~75.

typedef __bf16 bf16x8 __attribute__((ext_vector_type(8)));
typedef float f32x4 __attribute__((ext_vector_type(4)));

#define KTANH 2.8853900817779268f  // 2*log2(e), folded into pre-activation scale

__device__ __forceinline__ float tanh_pre(float z) {
    // input already scaled by KTANH: tanh = 1 - 2/(exp2(z)+1); saturates correctly at +-inf
    float e = __builtin_amdgcn_exp2f(z);
    float r = __builtin_amdgcn_rcpf(e + 1.0f);
    return __builtin_fmaf(-2.0f, r, 1.0f);
}

__device__ __forceinline__ float quad_sum(float v) {
    // sum over the 4 quads (lanes l, l^16, l^32, l^48) -- proven-correct shuffle path
    v += __shfl_xor(v, 16);
    v += __shfl_xor(v, 32);
    return v;
}

__global__ __launch_bounds__(256, 3) void damping_mfma(
    const float* __restrict__ x,
    const float* __restrict__ w_d1, const float* __restrict__ w_d2, const float* __restrict__ w_d3,
    const float* __restrict__ w_o1, const float* __restrict__ w_o2, const float* __restrict__ w_o3,
    const float* __restrict__ b_d1, const float* __restrict__ b_d2, const float* __restrict__ b_d3,
    const float* __restrict__ b_o1, const float* __restrict__ b_o2, const float* __restrict__ b_o3,
    float* __restrict__ out, int n_tiles)
{
    const int lane = threadIdx.x & 63;
    const int quad = lane >> 4;
    const int b16  = lane & 15;
    const int wid     = (int)((blockIdx.x * blockDim.x + threadIdx.x) >> 6);
    const int n_waves = (int)((gridDim.x * blockDim.x) >> 6);

    // ---------------- per-lane constant preload (once per wave) ----------------
    // Layer1 weights in B-frag k-order: k = quad*8 + j.  Pre-scaled by KTANH.
    float w1d0[8], w1d1[8], bd1[8], w1o0[8], w1o1[8], bo1[8];
    #pragma unroll
    for (int j = 0; j < 8; ++j) {
        int k = quad * 8 + j;
        w1d0[j] = w_d1[k] * KTANH; w1d1[j] = w_d1[32 + k] * KTANH; bd1[j] = b_d1[k] * KTANH;
        w1o0[j] = w_o1[k] * KTANH; w1o1[j] = w_o1[32 + k] * KTANH; bo1[j] = b_o1[k] * KTANH;
    }
    // Layer2 A-frags (pre-scaled): A[m][k] = KTANH*W^T[j=t*16+m][k]; m=b16, k=quad*8+j
    bf16x8 a_d2[2], a_o2[2];
    #pragma unroll
    for (int t = 0; t < 2; ++t) {
        #pragma unroll
        for (int j = 0; j < 8; ++j) {
            int k = quad * 8 + j;
            a_d2[t][j] = (__bf16)(w_d2[k * 32 + t * 16 + b16] * KTANH);
            a_o2[t][j] = (__bf16)(w_o2[k * 32 + t * 16 + b16] * KTANH);
        }
    }
    // Layer2 bias as MFMA C operand: reg i of tile t holds j = t*16 + quad*4 + i (pre-scaled)
    f32x4 cd[2], co[2];
    #pragma unroll
    for (int t = 0; t < 2; ++t) {
        #pragma unroll
        for (int i = 0; i < 4; ++i) {
            int jj = t * 16 + quad * 4 + i;
            cd[t][i] = b_d2[jj] * KTANH;
            co[t][i] = b_o2[jj] * KTANH;
        }
    }
    // Layer3 weights at this lane's 8 j-values: j = (i>>2)*16 + quad*4 + (i&3)  (unscaled)
    float w3d0[8], w3d1[8], w3o[8];
    #pragma unroll
    for (int i = 0; i < 8; ++i) {
        int jj = (i >> 2) * 16 + quad * 4 + (i & 3);
        w3d0[i] = w_d3[jj * 2]; w3d1[i] = w_d3[jj * 2 + 1];
        w3o[i]  = w_o3[jj];
    }
    const float bd3_0 = b_d3[0], bd3_1 = b_d3[1], bo3_0 = b_o3[0];

    const float2* x2 = (const float2*)x;
    int tile = wid;
    if (tile >= n_tiles) return;
    float2 xv = x2[tile * 16 + b16];

    for (; tile < n_tiles; tile += n_waves) {
        // software prefetch next tile's x (clamped; hides VMEM latency behind compute)
        int nt = tile + n_waves;
        nt = (nt < n_tiles) ? nt : tile;
        float2 xnext = x2[nt * 16 + b16];

        const float x0 = xv.x, x1 = xv.y;

        // -------- layer 1 (both branches), directly in B-frag layout --------
        float hd[8], ho[8];
        #pragma unroll
        for (int j = 0; j < 8; ++j) {
            hd[j] = tanh_pre(fmaf(x1, w1d1[j], fmaf(x0, w1d0[j], bd1[j])));
            ho[j] = tanh_pre(fmaf(x1, w1o1[j], fmaf(x0, w1o0[j], bo1[j])));
        }
        bf16x8 bfd, bfo;
        #pragma unroll
        for (int j = 0; j < 8; ++j) {
            bfd[j] = (__bf16)hd[j];   // compiler pairs these into v_cvt_pk_bf16_f32
            bfo[j] = (__bf16)ho[j];
        }

        // -------- layer 2: 4 independent MFMAs (2 j-tiles x 2 branches), bias in C --------
        f32x4 d0 = __builtin_amdgcn_mfma_f32_16x16x32_bf16(a_d2[0], bfd, cd[0], 0, 0, 0);
        f32x4 d1 = __builtin_amdgcn_mfma_f32_16x16x32_bf16(a_d2[1], bfd, cd[1], 0, 0, 0);
        f32x4 o0 = __builtin_amdgcn_mfma_f32_16x16x32_bf16(a_o2[0], bfo, co[0], 0, 0, 0);
        f32x4 o1 = __builtin_amdgcn_mfma_f32_16x16x32_bf16(a_o2[1], bfo, co[1], 0, 0, 0);

        // -------- layer 2 act + layer 3 partials --------
        float pd0 = 0.f, pd1 = 0.f, po = 0.f;
        #pragma unroll
        for (int i = 0; i < 8; ++i) {
            float h2d = tanh_pre(i < 4 ? d0[i] : d1[i - 4]);
            float h2o = tanh_pre(i < 4 ? o0[i] : o1[i - 4]);
            pd0 = fmaf(h2d, w3d0[i], pd0);
            pd1 = fmaf(h2d, w3d1[i], pd1);
            po  = fmaf(h2o, w3o[i], po);
        }
        // reduce across the 4 quads (same b16)
        pd0 = quad_sum(pd0);
        pd1 = quad_sum(pd1);
        po  = quad_sum(po);

        // -------- epilogue --------
        float d30 = pd0 + bd3_0, d31 = pd1 + bd3_1, c = po + bo3_0;
        float a = (fmaxf(d30, 0.f) + 0.001f) * x0;
        float b = (fmaxf(d31, 0.f) + 0.001f) * x1;
        float D0 = fmaf(a * a, x0, a * c * x1);
        float D1 = fmaf(a * c, x0, fmaf(c, c, b * b) * x1);

        if (quad == 0) ((float2*)out)[tile * 16 + b16] = make_float2(D0, D1);
        xv = xnext;
    }
}

extern "C" void kernel_launch(void* const* d_in, const int* in_sizes, int n_in,
                              void* d_out, int out_size, void* d_ws, size_t ws_size,
                              hipStream_t stream) {
    const float* x    = (const float*)d_in[0];
    const float* w_d1 = (const float*)d_in[1];
    const float* w_d2 = (const float*)d_in[2];
    const float* w_d3 = (const float*)d_in[3];
    const float* w_o1 = (const float*)d_in[4];
    const float* w_o2 = (const float*)d_in[5];
    const float* w_o3 = (const float*)d_in[6];
    const float* b_d1 = (const float*)d_in[7];
    const float* b_d2 = (const float*)d_in[8];
    const float* b_d3 = (const float*)d_in[9];
    const float* b_o1 = (const float*)d_in[10];
    const float* b_o2 = (const float*)d_in[11];
    const float* b_o3 = (const float*)d_in[12];
    float* out = (float*)d_out;

    int n = in_sizes[0] / 2;         // rows
    int n_tiles = n / 16;            // 16 rows per wave-iteration
    // VGPR=76 rounds to 80 -> HW residency 512/80 = 6 waves/SIMD = 6 blocks/CU.
    // grid 1536 = 6 blocks/CU exactly fills it (R7's 1024 left 1/3 of the
    // VGPR-allowed residency unused). 65536 tiles / 6144 waves = ~10.7 iters/wave.
    int blocks_needed = (n_tiles + 3) / 4;
    int grid = blocks_needed < 1536 ? blocks_needed : 1536;
    damping_mfma<<<grid, 256, 0, stream>>>(
        x, w_d1, w_d2, w_d3, w_o1, w_o2, w_o3,
        b_d1, b_d2, b_d3, b_o1, b_o2, b_o3, out, n_tiles);
}

// Round 12
// 120.540 us; speedup vs baseline: 2.2263x; 1.0043x over previous
//
#include <hip/hip_runtime.h>

// Batch-as-N MFMA mapping: Y^T[j,b] = W^T[j,k] @ H^T[k,b] via mfma_f32_16x16x32_bf16.
// b (batch row within 16-tile) lives in lane&15 for the ENTIRE network:
//   B-frag (activations): lane holds n=lane&15, k = quad*8 + 0..7   (quad = lane>>4)
//   D      (outputs):     lane holds n=lane&15, j = t*16 + quad*4 + reg
// Layer1 (2->32) computes its 8 outputs directly in B-frag layout (no shuffle).
// Layer3 (32->{2,1}) is per-lane partials over the lane's 8 j-values + quad-reduce
// via __shfl_xor(16/32) (proven correct across all passing rounds).
//
// Session ledger:
//  - R2 (197us): VALU cuts validated; launch_bounds(256,8) -> VGPR=32 massive spill.
//  - R3/R4 (failed): permlane swap w/ duplicated operand = regalloc hazard. Abandoned.
//  - R6 (53us): launch_bounds(256,4) -> VGPR=64 mild spill canceled gains.
//  - R7 (47us): launch_bounds(256,3) clean @ VGPR=76, grid 1024. VALUBusy 63.
//  - R8 (47us, flat): grid 1536 (6 blk/CU) -> NO change. Occupancy counter flat.
//    Conclusion: issue-port-bound, not TLP-bound. Measured VALU busy ~1110 cyc/iter
//    matches 64 trans ops @ ~16cyc each -> tanh transcendentals ARE the kernel.
//  - R9/R10/R11: infra failures (container x2; acquisition timeout x2).
//    This is an identical resubmission of the batched-rcp experiment.
//  - R12 (this): 4-way batched reciprocal: rcp(e0*e1*e2*e3) + 9 muls recovers all
//    four 1/ei -> 32 rcp/iter becomes 8 rcp + 72 mul. Predicted -22% (16cyc trans
//    model) or -4% (8cyc model) -- this round also discriminates the two models.
//    Overflow-safe: layer-2 |z|<=18.5 -> product <= 2^74 < f32 max.

typedef __bf16 bf16x8 __attribute__((ext_vector_type(8)));
typedef float f32x4 __attribute__((ext_vector_type(4)));

#define KTANH 2.8853900817779268f  // 2*log2(e), folded into pre-activation scale

// 4 tanh with ONE v_rcp: h_i = 1 - 2/(exp2(z_i)+1), reciprocals batched via
// the product trick (exact f32 identity up to ~2 ulp, not an approximation).
__device__ __forceinline__ void tanh4_pre(float z0, float z1, float z2, float z3,
                                          float& h0, float& h1, float& h2, float& h3) {
    float e0 = __builtin_amdgcn_exp2f(z0) + 1.0f;
    float e1 = __builtin_amdgcn_exp2f(z1) + 1.0f;
    float e2 = __builtin_amdgcn_exp2f(z2) + 1.0f;
    float e3 = __builtin_amdgcn_exp2f(z3) + 1.0f;
    float p2 = e0 * e1;
    float p3 = p2 * e2;
    float p4 = p3 * e3;
    float r4 = __builtin_amdgcn_rcpf(p4);   // 1/(e0 e1 e2 e3)
    float i3 = p3 * r4;                     // 1/e3
    float r3 = r4 * e3;                     // 1/(e0 e1 e2)
    float i2 = p2 * r3;                     // 1/e2
    float r2 = r3 * e2;                     // 1/(e0 e1)
    float i1 = e0 * r2;                     // 1/e1
    float i0 = e1 * r2;                     // 1/e0
    h0 = __builtin_fmaf(-2.0f, i0, 1.0f);
    h1 = __builtin_fmaf(-2.0f, i1, 1.0f);
    h2 = __builtin_fmaf(-2.0f, i2, 1.0f);
    h3 = __builtin_fmaf(-2.0f, i3, 1.0f);
}

__device__ __forceinline__ float quad_sum(float v) {
    // sum over the 4 quads (lanes l, l^16, l^32, l^48) -- proven-correct shuffle path
    v += __shfl_xor(v, 16);
    v += __shfl_xor(v, 32);
    return v;
}

__global__ __launch_bounds__(256, 3) void damping_mfma(
    const float* __restrict__ x,
    const float* __restrict__ w_d1, const float* __restrict__ w_d2, const float* __restrict__ w_d3,
    const float* __restrict__ w_o1, const float* __restrict__ w_o2, const float* __restrict__ w_o3,
    const float* __restrict__ b_d1, const float* __restrict__ b_d2, const float* __restrict__ b_d3,
    const float* __restrict__ b_o1, const float* __restrict__ b_o2, const float* __restrict__ b_o3,
    float* __restrict__ out, int n_tiles)
{
    const int lane = threadIdx.x & 63;
    const int quad = lane >> 4;
    const int b16  = lane & 15;
    const int wid     = (int)((blockIdx.x * blockDim.x + threadIdx.x) >> 6);
    const int n_waves = (int)((gridDim.x * blockDim.x) >> 6);

    // ---------------- per-lane constant preload (once per wave) ----------------
    // Layer1 weights in B-frag k-order: k = quad*8 + j.  Pre-scaled by KTANH.
    float w1d0[8], w1d1[8], bd1[8], w1o0[8], w1o1[8], bo1[8];
    #pragma unroll
    for (int j = 0; j < 8; ++j) {
        int k = quad * 8 + j;
        w1d0[j] = w_d1[k] * KTANH; w1d1[j] = w_d1[32 + k] * KTANH; bd1[j] = b_d1[k] * KTANH;
        w1o0[j] = w_o1[k] * KTANH; w1o1[j] = w_o1[32 + k] * KTANH; bo1[j] = b_o1[k] * KTANH;
    }
    // Layer2 A-frags (pre-scaled): A[m][k] = KTANH*W^T[j=t*16+m][k]; m=b16, k=quad*8+j
    bf16x8 a_d2[2], a_o2[2];
    #pragma unroll
    for (int t = 0; t < 2; ++t) {
        #pragma unroll
        for (int j = 0; j < 8; ++j) {
            int k = quad * 8 + j;
            a_d2[t][j] = (__bf16)(w_d2[k * 32 + t * 16 + b16] * KTANH);
            a_o2[t][j] = (__bf16)(w_o2[k * 32 + t * 16 + b16] * KTANH);
        }
    }
    // Layer2 bias as MFMA C operand: reg i of tile t holds j = t*16 + quad*4 + i (pre-scaled)
    f32x4 cd[2], co[2];
    #pragma unroll
    for (int t = 0; t < 2; ++t) {
        #pragma unroll
        for (int i = 0; i < 4; ++i) {
            int jj = t * 16 + quad * 4 + i;
            cd[t][i] = b_d2[jj] * KTANH;
            co[t][i] = b_o2[jj] * KTANH;
        }
    }
    // Layer3 weights at this lane's 8 j-values: j = (i>>2)*16 + quad*4 + (i&3)  (unscaled)
    float w3d0[8], w3d1[8], w3o[8];
    #pragma unroll
    for (int i = 0; i < 8; ++i) {
        int jj = (i >> 2) * 16 + quad * 4 + (i & 3);
        w3d0[i] = w_d3[jj * 2]; w3d1[i] = w_d3[jj * 2 + 1];
        w3o[i]  = w_o3[jj];
    }
    const float bd3_0 = b_d3[0], bd3_1 = b_d3[1], bo3_0 = b_o3[0];

    const float2* x2 = (const float2*)x;
    int tile = wid;
    if (tile >= n_tiles) return;
    float2 xv = x2[tile * 16 + b16];

    for (; tile < n_tiles; tile += n_waves) {
        // software prefetch next tile's x (clamped; hides VMEM latency behind compute)
        int nt = tile + n_waves;
        nt = (nt < n_tiles) ? nt : tile;
        float2 xnext = x2[nt * 16 + b16];

        const float x0 = xv.x, x1 = xv.y;

        // -------- layer 1 (both branches), directly in B-frag layout --------
        float hd[8], ho[8];
        {
            float zd[8], zo[8];
            #pragma unroll
            for (int j = 0; j < 8; ++j) {
                zd[j] = fmaf(x1, w1d1[j], fmaf(x0, w1d0[j], bd1[j]));
                zo[j] = fmaf(x1, w1o1[j], fmaf(x0, w1o0[j], bo1[j]));
            }
            tanh4_pre(zd[0], zd[1], zd[2], zd[3], hd[0], hd[1], hd[2], hd[3]);
            tanh4_pre(zd[4], zd[5], zd[6], zd[7], hd[4], hd[5], hd[6], hd[7]);
            tanh4_pre(zo[0], zo[1], zo[2], zo[3], ho[0], ho[1], ho[2], ho[3]);
            tanh4_pre(zo[4], zo[5], zo[6], zo[7], ho[4], ho[5], ho[6], ho[7]);
        }
        bf16x8 bfd, bfo;
        #pragma unroll
        for (int j = 0; j < 8; ++j) {
            bfd[j] = (__bf16)hd[j];   // compiler pairs these into v_cvt_pk_bf16_f32
            bfo[j] = (__bf16)ho[j];
        }

        // -------- layer 2: 4 independent MFMAs (2 j-tiles x 2 branches), bias in C --------
        f32x4 d0 = __builtin_amdgcn_mfma_f32_16x16x32_bf16(a_d2[0], bfd, cd[0], 0, 0, 0);
        f32x4 d1 = __builtin_amdgcn_mfma_f32_16x16x32_bf16(a_d2[1], bfd, cd[1], 0, 0, 0);
        f32x4 o0 = __builtin_amdgcn_mfma_f32_16x16x32_bf16(a_o2[0], bfo, co[0], 0, 0, 0);
        f32x4 o1 = __builtin_amdgcn_mfma_f32_16x16x32_bf16(a_o2[1], bfo, co[1], 0, 0, 0);

        // -------- layer 2 act (batched-rcp tanh) + layer 3 partials --------
        float h2d[8], h2o[8];
        tanh4_pre(d0[0], d0[1], d0[2], d0[3], h2d[0], h2d[1], h2d[2], h2d[3]);
        tanh4_pre(d1[0], d1[1], d1[2], d1[3], h2d[4], h2d[5], h2d[6], h2d[7]);
        tanh4_pre(o0[0], o0[1], o0[2], o0[3], h2o[0], h2o[1], h2o[2], h2o[3]);
        tanh4_pre(o1[0], o1[1], o1[2], o1[3], h2o[4], h2o[5], h2o[6], h2o[7]);

        float pd0 = 0.f, pd1 = 0.f, po = 0.f;
        #pragma unroll
        for (int i = 0; i < 8; ++i) {
            pd0 = fmaf(h2d[i], w3d0[i], pd0);
            pd1 = fmaf(h2d[i], w3d1[i], pd1);
            po  = fmaf(h2o[i], w3o[i], po);
        }
        // reduce across the 4 quads (same b16)
        pd0 = quad_sum(pd0);
        pd1 = quad_sum(pd1);
        po  = quad_sum(po);

        // -------- epilogue --------
        float d30 = pd0 + bd3_0, d31 = pd1 + bd3_1, c = po + bo3_0;
        float a = (fmaxf(d30, 0.f) + 0.001f) * x0;
        float b = (fmaxf(d31, 0.f) + 0.001f) * x1;
        float D0 = fmaf(a * a, x0, a * c * x1);
        float D1 = fmaf(a * c, x0, fmaf(c, c, b * b) * x1);

        if (quad == 0) ((float2*)out)[tile * 16 + b16] = make_float2(D0, D1);
        xv = xnext;
    }
}

extern "C" void kernel_launch(void* const* d_in, const int* in_sizes, int n_in,
                              void* d_out, int out_size, void* d_ws, size_t ws_size,
                              hipStream_t stream) {
    const float* x    = (const float*)d_in[0];
    const float* w_d1 = (const float*)d_in[1];
    const float* w_d2 = (const float*)d_in[2];
    const float* w_d3 = (const float*)d_in[3];
    const float* w_o1 = (const float*)d_in[4];
    const float* w_o2 = (const float*)d_in[5];
    const float* w_o3 = (const float*)d_in[6];
    const float* b_d1 = (const float*)d_in[7];
    const float* b_d2 = (const float*)d_in[8];
    const float* b_d3 = (const float*)d_in[9];
    const float* b_o1 = (const float*)d_in[10];
    const float* b_o2 = (const float*)d_in[11];
    const float* b_o3 = (const float*)d_in[12];
    float* out = (float*)d_out;

    int n = in_sizes[0] / 2;         // rows
    int n_tiles = n / 16;            // 16 rows per wave-iteration
    // grid 1536 (6 blk/CU) -- R8 showed occupancy-neutral vs 1024; kept constant
    // so this round isolates the batched-rcp change only.
    int blocks_needed = (n_tiles + 3) / 4;
    int grid = blocks_needed < 1536 ? blocks_needed : 1536;
    damping_mfma<<<grid, 256, 0, stream>>>(
        x, w_d1, w_d2, w_d3, w_o1, w_o2, w_o3,
        b_d1, b_d2, b_d3, b_o1, b_o2, b_o3, out, n_tiles);
}

// Round 14
// 119.221 us; speedup vs baseline: 2.2509x; 1.0111x over previous
//
#include <hip/hip_runtime.h>

// Batch-as-N MFMA mapping: Y^T[j,b] = W^T[j,k] @ H^T[k,b] via mfma_f32_16x16x32_bf16.
// b (batch row within 16-tile) lives in lane&15 for the ENTIRE network.
// Layer1 (2->32) computes its 8 outputs directly in B-frag layout (no shuffle).
// Layer2 output neurons are PERMUTED (p(t,r) = (r>>2)*8 + t*4 + (r&3)) so the
// MFMA D-layout output IS a B-frag in k-order: lane (quad,b16) holds neurons
// quad*8+0..7 after tanh. Layer3 (32->{2,1}) is then 2 MFMAs (A=W3^T rows 0..1/0,
// bias in C); d30/d31/c land in quad-0 regs 0/1/0 -- no shuffles at all.
//
// Session ledger:
//  - R2 (197us): VALU cuts validated; launch_bounds(256,8) -> VGPR=32 massive spill.
//  - R3/R4 (failed): permlane swap w/ duplicated operand = regalloc hazard. Abandoned.
//  - R6 (53us): launch_bounds(256,4) -> VGPR=64 mild spill canceled gains.
//  - R7 (47us): launch_bounds(256,3) clean @ VGPR=76, grid 1024. VALUBusy 63.
//  - R8 (47us, flat): grid 1536 -> no change. Issue-bound, not TLP-bound.
//  - R12 (45.4us): 4-way batched rcp (32rcp -> 8rcp+72mul) = -3.4%. Trans ops are
//    ~8cyc (model discriminated). VGPR=72 < ~107 live constants -> compiler
//    re-fetches constants per-iter from L1. Full-rate VALU now dominates.
//  - R13: GPUAcquisitionTimeout (infra). This is an identical resubmission.
//  - R14 (this): layer-3-as-MFMA via neuron permutation. Deletes 24 fmaf +
//    6 shfl_xor (serial DS chain) + 3 adds + 24 w3 VGPRs; adds 8 cvt_pk +
//    2 MFMAs on the idle matrix pipe. Risk: h2/w3 through bf16 -> absmax
//    predicted <=0.045 vs threshold 0.0516. Fallback: f32 fmaf layer-3.

typedef __bf16 bf16x8 __attribute__((ext_vector_type(8)));
typedef float f32x4 __attribute__((ext_vector_type(4)));

#define KTANH 2.8853900817779268f  // 2*log2(e), folded into pre-activation scale

// 4 tanh with ONE v_rcp: h_i = 1 - 2/(exp2(z_i)+1), reciprocals batched via
// the product trick (exact f32 identity up to ~2 ulp, not an approximation).
__device__ __forceinline__ void tanh4_pre(float z0, float z1, float z2, float z3,
                                          float& h0, float& h1, float& h2, float& h3) {
    float e0 = __builtin_amdgcn_exp2f(z0) + 1.0f;
    float e1 = __builtin_amdgcn_exp2f(z1) + 1.0f;
    float e2 = __builtin_amdgcn_exp2f(z2) + 1.0f;
    float e3 = __builtin_amdgcn_exp2f(z3) + 1.0f;
    float p2 = e0 * e1;
    float p3 = p2 * e2;
    float p4 = p3 * e3;
    float r4 = __builtin_amdgcn_rcpf(p4);   // 1/(e0 e1 e2 e3)
    float i3 = p3 * r4;                     // 1/e3
    float r3 = r4 * e3;                     // 1/(e0 e1 e2)
    float i2 = p2 * r3;                     // 1/e2
    float r2 = r3 * e2;                     // 1/(e0 e1)
    float i1 = e0 * r2;                     // 1/e1
    float i0 = e1 * r2;                     // 1/e0
    h0 = __builtin_fmaf(-2.0f, i0, 1.0f);
    h1 = __builtin_fmaf(-2.0f, i1, 1.0f);
    h2 = __builtin_fmaf(-2.0f, i2, 1.0f);
    h3 = __builtin_fmaf(-2.0f, i3, 1.0f);
}

__global__ __launch_bounds__(256, 3) void damping_mfma(
    const float* __restrict__ x,
    const float* __restrict__ w_d1, const float* __restrict__ w_d2, const float* __restrict__ w_d3,
    const float* __restrict__ w_o1, const float* __restrict__ w_o2, const float* __restrict__ w_o3,
    const float* __restrict__ b_d1, const float* __restrict__ b_d2, const float* __restrict__ b_d3,
    const float* __restrict__ b_o1, const float* __restrict__ b_o2, const float* __restrict__ b_o3,
    float* __restrict__ out, int n_tiles)
{
    const int lane = threadIdx.x & 63;
    const int quad = lane >> 4;
    const int b16  = lane & 15;
    const int wid     = (int)((blockIdx.x * blockDim.x + threadIdx.x) >> 6);
    const int n_waves = (int)((gridDim.x * blockDim.x) >> 6);

    // ---------------- per-lane constant preload (once per wave) ----------------
    // Layer1 weights in B-frag k-order: k = quad*8 + j.  Pre-scaled by KTANH.
    float w1d0[8], w1d1[8], bd1[8], w1o0[8], w1o1[8], bo1[8];
    #pragma unroll
    for (int j = 0; j < 8; ++j) {
        int k = quad * 8 + j;
        w1d0[j] = w_d1[k] * KTANH; w1d1[j] = w_d1[32 + k] * KTANH; bd1[j] = b_d1[k] * KTANH;
        w1o0[j] = w_o1[k] * KTANH; w1o1[j] = w_o1[32 + k] * KTANH; bo1[j] = b_o1[k] * KTANH;
    }
    // Layer2 A-frags, PERMUTED columns: A-row m of tile t computes hidden2 neuron
    // p(t,m) = (m>>2)*8 + t*4 + (m&3).  A[m][k] at lane m=b16, k=quad*8+j.
    bf16x8 a_d2[2], a_o2[2];
    const int pm0 = ((b16 >> 2) * 8) + (b16 & 3);   // p(0, b16); p(1,m) = pm0 + 4
    #pragma unroll
    for (int t = 0; t < 2; ++t) {
        #pragma unroll
        for (int j = 0; j < 8; ++j) {
            int k = quad * 8 + j;
            a_d2[t][j] = (__bf16)(w_d2[k * 32 + pm0 + t * 4] * KTANH);
            a_o2[t][j] = (__bf16)(w_o2[k * 32 + pm0 + t * 4] * KTANH);
        }
    }
    // Layer2 bias as MFMA C: reg i of tile t is D-row quad*4+i = neuron quad*8+t*4+i
    f32x4 cd[2], co[2];
    #pragma unroll
    for (int t = 0; t < 2; ++t) {
        #pragma unroll
        for (int i = 0; i < 4; ++i) {
            int nn = quad * 8 + t * 4 + i;
            cd[t][i] = b_d2[nn] * KTANH;
            co[t][i] = b_o2[nn] * KTANH;
        }
    }
    // Layer3 A-frags: A[m][k] = W3^T[m][k] = w3[k][m]; k = quad*8+j, m = b16.
    // Rows m>=2 (d) / m>=1 (o) are zero.  (B-frag k position == neuron k by the
    // permutation above, so w_d3/w_o3 need NO reindexing.)
    bf16x8 a_d3, a_o3;
    #pragma unroll
    for (int j = 0; j < 8; ++j) {
        int k = quad * 8 + j;
        a_d3[j] = (b16 < 2) ? (__bf16)w_d3[k * 2 + b16] : (__bf16)0.0f;
        a_o3[j] = (b16 == 0) ? (__bf16)w_o3[k] : (__bf16)0.0f;
    }
    // Layer3 bias as MFMA C: D-row r = quad*4+i; bias lives at r=0,1 (d) / r=0 (o)
    f32x4 cd3, co3;
    #pragma unroll
    for (int i = 0; i < 4; ++i) {
        int r = quad * 4 + i;
        cd3[i] = (r == 0) ? b_d3[0] : (r == 1) ? b_d3[1] : 0.0f;
        co3[i] = (r == 0) ? b_o3[0] : 0.0f;
    }

    const float2* x2 = (const float2*)x;
    int tile = wid;
    if (tile >= n_tiles) return;
    float2 xv = x2[tile * 16 + b16];

    for (; tile < n_tiles; tile += n_waves) {
        // software prefetch next tile's x (clamped; hides VMEM latency behind compute)
        int nt = tile + n_waves;
        nt = (nt < n_tiles) ? nt : tile;
        float2 xnext = x2[nt * 16 + b16];

        const float x0 = xv.x, x1 = xv.y;

        // -------- layer 1 (both branches), directly in B-frag layout --------
        float hd[8], ho[8];
        {
            float zd[8], zo[8];
            #pragma unroll
            for (int j = 0; j < 8; ++j) {
                zd[j] = fmaf(x1, w1d1[j], fmaf(x0, w1d0[j], bd1[j]));
                zo[j] = fmaf(x1, w1o1[j], fmaf(x0, w1o0[j], bo1[j]));
            }
            tanh4_pre(zd[0], zd[1], zd[2], zd[3], hd[0], hd[1], hd[2], hd[3]);
            tanh4_pre(zd[4], zd[5], zd[6], zd[7], hd[4], hd[5], hd[6], hd[7]);
            tanh4_pre(zo[0], zo[1], zo[2], zo[3], ho[0], ho[1], ho[2], ho[3]);
            tanh4_pre(zo[4], zo[5], zo[6], zo[7], ho[4], ho[5], ho[6], ho[7]);
        }
        bf16x8 bfd, bfo;
        #pragma unroll
        for (int j = 0; j < 8; ++j) {
            bfd[j] = (__bf16)hd[j];   // pairs into v_cvt_pk_bf16_f32
            bfo[j] = (__bf16)ho[j];
        }

        // -------- layer 2: 4 MFMAs (2 j-tiles x 2 branches), bias in C --------
        f32x4 d0 = __builtin_amdgcn_mfma_f32_16x16x32_bf16(a_d2[0], bfd, cd[0], 0, 0, 0);
        f32x4 d1 = __builtin_amdgcn_mfma_f32_16x16x32_bf16(a_d2[1], bfd, cd[1], 0, 0, 0);
        f32x4 o0 = __builtin_amdgcn_mfma_f32_16x16x32_bf16(a_o2[0], bfo, co[0], 0, 0, 0);
        f32x4 o1 = __builtin_amdgcn_mfma_f32_16x16x32_bf16(a_o2[1], bfo, co[1], 0, 0, 0);

        // -------- layer 2 act: lane now holds neurons quad*8+0..7 (B-frag order)
        float h2d[8], h2o[8];
        tanh4_pre(d0[0], d0[1], d0[2], d0[3], h2d[0], h2d[1], h2d[2], h2d[3]);
        tanh4_pre(d1[0], d1[1], d1[2], d1[3], h2d[4], h2d[5], h2d[6], h2d[7]);
        tanh4_pre(o0[0], o0[1], o0[2], o0[3], h2o[0], h2o[1], h2o[2], h2o[3]);
        tanh4_pre(o1[0], o1[1], o1[2], o1[3], h2o[4], h2o[5], h2o[6], h2o[7]);

        bf16x8 b3d, b3o;
        #pragma unroll
        for (int j = 0; j < 8; ++j) {
            b3d[j] = (__bf16)h2d[j];
            b3o[j] = (__bf16)h2o[j];
        }

        // -------- layer 3: 2 MFMAs, no shuffles. quad 0: rd[0]=d30, rd[1]=d31, ro[0]=c
        f32x4 rd = __builtin_amdgcn_mfma_f32_16x16x32_bf16(a_d3, b3d, cd3, 0, 0, 0);
        f32x4 ro = __builtin_amdgcn_mfma_f32_16x16x32_bf16(a_o3, b3o, co3, 0, 0, 0);

        // -------- epilogue (valid on quad 0; other quads compute garbage, unused) --------
        float d30 = rd[0], d31 = rd[1], c = ro[0];
        float a = (fmaxf(d30, 0.f) + 0.001f) * x0;
        float b = (fmaxf(d31, 0.f) + 0.001f) * x1;
        float D0 = fmaf(a * a, x0, a * c * x1);
        float D1 = fmaf(a * c, x0, fmaf(c, c, b * b) * x1);

        if (quad == 0) ((float2*)out)[tile * 16 + b16] = make_float2(D0, D1);
        xv = xnext;
    }
}

extern "C" void kernel_launch(void* const* d_in, const int* in_sizes, int n_in,
                              void* d_out, int out_size, void* d_ws, size_t ws_size,
                              hipStream_t stream) {
    const float* x    = (const float*)d_in[0];
    const float* w_d1 = (const float*)d_in[1];
    const float* w_d2 = (const float*)d_in[2];
    const float* w_d3 = (const float*)d_in[3];
    const float* w_o1 = (const float*)d_in[4];
    const float* w_o2 = (const float*)d_in[5];
    const float* w_o3 = (const float*)d_in[6];
    const float* b_d1 = (const float*)d_in[7];
    const float* b_d2 = (const float*)d_in[8];
    const float* b_d3 = (const float*)d_in[9];
    const float* b_o1 = (const float*)d_in[10];
    const float* b_o2 = (const float*)d_in[11];
    const float* b_o3 = (const float*)d_in[12];
    float* out = (float*)d_out;

    int n = in_sizes[0] / 2;         // rows
    int n_tiles = n / 16;            // 16 rows per wave-iteration
    // grid 1536 (6 blk/CU) -- R8 showed occupancy-insensitive; held constant so
    // this round isolates the layer-3-as-MFMA change only.
    int blocks_needed = (n_tiles + 3) / 4;
    int grid = blocks_needed < 1536 ? blocks_needed : 1536;
    damping_mfma<<<grid, 256, 0, stream>>>(
        x, w_d1, w_d2, w_d3, w_o1, w_o2, w_o3,
        b_d1, b_d2, b_d3, b_o1, b_o2, b_o3, out, n_tiles);
}

// Round 16
// 117.774 us; speedup vs baseline: 2.2786x; 1.0123x over previous
//
#include <hip/hip_runtime.h>

// Batch-as-N MFMA mapping: Y^T[j,b] = W^T[j,k] @ H^T[k,b] via mfma_f32_16x16x32_bf16.
// b (batch row within 16-tile) lives in lane&15 for the ENTIRE network:
//   B-frag (activations): lane holds n=lane&15, k = quad*8 + 0..7   (quad = lane>>4)
//   D      (outputs):     lane holds n=lane&15, j = t*16 + quad*4 + reg
// Layer1 (2->32) computes its 8 outputs directly in B-frag layout (no shuffle).
// Layer3 (32->{2,1}) is per-lane partials + quad-reduce via __shfl_xor(16/32).
//
// Session ledger:
//  - R2 (197us): VALU cuts validated; launch_bounds(256,8) -> VGPR=32 massive spill.
//  - R3/R4 (failed): permlane swap w/ duplicated operand = regalloc hazard. Abandoned.
//  - R6 (53us): launch_bounds(256,4) -> VGPR=64 mild spill canceled gains.
//  - R7 (47us): launch_bounds(256,3) clean @ VGPR=76. VALUBusy 63.
//  - R8 (47us, flat): grid 1536 -> no change. Issue-bound, NOT TLP-bound.
//  - R12 (45.4us, best): 4-way batched rcp. Trans ~8cyc confirmed. VALUBusy 68.5.
//  - R14 (48.7us, REGRESSION): layer-3-as-MFMA lengthened the serial chain; at thin
//    TLP the MFMA latency is naked. Reverted to fmaf+shfl layer-3.
//  - R15: GPUAcquisitionTimeout (infra). This is an identical resubmission.
//  - R16 (this): R12 structure + ILP=2 (two tiles/iter, independent chains overlap
//    the ~31% idle issue). Cap ~170 VGPR @ (256,3) fits ~107 consts + 2x temps.
//    Grid 1024 = 4096 waves -> exactly 8 pair-iters/wave.
//    Spill tripwire: FETCH/WRITE must stay 4.2/8.2 MB.

typedef __bf16 bf16x8 __attribute__((ext_vector_type(8)));
typedef float f32x4 __attribute__((ext_vector_type(4)));

#define KTANH 2.8853900817779268f  // 2*log2(e), folded into pre-activation scale

// 4 tanh with ONE v_rcp: h_i = 1 - 2/(exp2(z_i)+1), reciprocals batched via
// the product trick (exact f32 identity up to ~2 ulp, not an approximation).
__device__ __forceinline__ void tanh4_pre(float z0, float z1, float z2, float z3,
                                          float& h0, float& h1, float& h2, float& h3) {
    float e0 = __builtin_amdgcn_exp2f(z0) + 1.0f;
    float e1 = __builtin_amdgcn_exp2f(z1) + 1.0f;
    float e2 = __builtin_amdgcn_exp2f(z2) + 1.0f;
    float e3 = __builtin_amdgcn_exp2f(z3) + 1.0f;
    float p2 = e0 * e1;
    float p3 = p2 * e2;
    float p4 = p3 * e3;
    float r4 = __builtin_amdgcn_rcpf(p4);   // 1/(e0 e1 e2 e3)
    float i3 = p3 * r4;                     // 1/e3
    float r3 = r4 * e3;                     // 1/(e0 e1 e2)
    float i2 = p2 * r3;                     // 1/e2
    float r2 = r3 * e2;                     // 1/(e0 e1)
    float i1 = e0 * r2;                     // 1/e1
    float i0 = e1 * r2;                     // 1/e0
    h0 = __builtin_fmaf(-2.0f, i0, 1.0f);
    h1 = __builtin_fmaf(-2.0f, i1, 1.0f);
    h2 = __builtin_fmaf(-2.0f, i2, 1.0f);
    h3 = __builtin_fmaf(-2.0f, i3, 1.0f);
}

// two-phase butterfly over six values: shuffle latencies overlap within each phase
__device__ __forceinline__ void quad_sum6(float& a, float& b, float& c,
                                          float& d, float& e, float& f) {
    a += __shfl_xor(a, 16); b += __shfl_xor(b, 16); c += __shfl_xor(c, 16);
    d += __shfl_xor(d, 16); e += __shfl_xor(e, 16); f += __shfl_xor(f, 16);
    a += __shfl_xor(a, 32); b += __shfl_xor(b, 32); c += __shfl_xor(c, 32);
    d += __shfl_xor(d, 32); e += __shfl_xor(e, 32); f += __shfl_xor(f, 32);
}

__global__ __launch_bounds__(256, 3) void damping_mfma(
    const float* __restrict__ x,
    const float* __restrict__ w_d1, const float* __restrict__ w_d2, const float* __restrict__ w_d3,
    const float* __restrict__ w_o1, const float* __restrict__ w_o2, const float* __restrict__ w_o3,
    const float* __restrict__ b_d1, const float* __restrict__ b_d2, const float* __restrict__ b_d3,
    const float* __restrict__ b_o1, const float* __restrict__ b_o2, const float* __restrict__ b_o3,
    float* __restrict__ out, int n_tiles)
{
    const int lane = threadIdx.x & 63;
    const int quad = lane >> 4;
    const int b16  = lane & 15;
    const int wid     = (int)((blockIdx.x * blockDim.x + threadIdx.x) >> 6);
    const int n_waves = (int)((gridDim.x * blockDim.x) >> 6);

    // ---------------- per-lane constant preload (once per wave) ----------------
    // Layer1 weights in B-frag k-order: k = quad*8 + j.  Pre-scaled by KTANH.
    float w1d0[8], w1d1[8], bd1[8], w1o0[8], w1o1[8], bo1[8];
    #pragma unroll
    for (int j = 0; j < 8; ++j) {
        int k = quad * 8 + j;
        w1d0[j] = w_d1[k] * KTANH; w1d1[j] = w_d1[32 + k] * KTANH; bd1[j] = b_d1[k] * KTANH;
        w1o0[j] = w_o1[k] * KTANH; w1o1[j] = w_o1[32 + k] * KTANH; bo1[j] = b_o1[k] * KTANH;
    }
    // Layer2 A-frags (pre-scaled): A[m][k] = KTANH*W^T[j=t*16+m][k]; m=b16, k=quad*8+j
    bf16x8 a_d2[2], a_o2[2];
    #pragma unroll
    for (int t = 0; t < 2; ++t) {
        #pragma unroll
        for (int j = 0; j < 8; ++j) {
            int k = quad * 8 + j;
            a_d2[t][j] = (__bf16)(w_d2[k * 32 + t * 16 + b16] * KTANH);
            a_o2[t][j] = (__bf16)(w_o2[k * 32 + t * 16 + b16] * KTANH);
        }
    }
    // Layer2 bias as MFMA C operand: reg i of tile t holds j = t*16 + quad*4 + i (pre-scaled)
    f32x4 cd[2], co[2];
    #pragma unroll
    for (int t = 0; t < 2; ++t) {
        #pragma unroll
        for (int i = 0; i < 4; ++i) {
            int jj = t * 16 + quad * 4 + i;
            cd[t][i] = b_d2[jj] * KTANH;
            co[t][i] = b_o2[jj] * KTANH;
        }
    }
    // Layer3 weights at this lane's 8 j-values: j = (i>>2)*16 + quad*4 + (i&3)  (unscaled)
    float w3d0[8], w3d1[8], w3o[8];
    #pragma unroll
    for (int i = 0; i < 8; ++i) {
        int jj = (i >> 2) * 16 + quad * 4 + (i & 3);
        w3d0[i] = w_d3[jj * 2]; w3d1[i] = w_d3[jj * 2 + 1];
        w3o[i]  = w_o3[jj];
    }
    const float bd3_0 = b_d3[0], bd3_1 = b_d3[1], bo3_0 = b_o3[0];

    const float2* x2 = (const float2*)x;
    float2* o2v = (float2*)out;

    // pair-of-tiles loop: wave processes tiles {2p, 2p+1} per iteration
    const int n_pairs = (n_tiles + 1) >> 1;
    int p = wid;
    if (p >= n_pairs) return;
    int tB0 = (2 * p + 1 < n_tiles) ? (2 * p + 1) : (2 * p);
    float2 xvA = x2[2 * p * 16 + b16];
    float2 xvB = x2[tB0 * 16 + b16];

    for (; p < n_pairs; p += n_waves) {
        // software prefetch next pair's x (clamped)
        int np = p + n_waves; np = (np < n_pairs) ? np : p;
        int ntA = 2 * np;
        int ntB = (ntA + 1 < n_tiles) ? (ntA + 1) : ntA;
        float2 xnA = x2[ntA * 16 + b16];
        float2 xnB = x2[ntB * 16 + b16];

        const float xA0 = xvA.x, xA1 = xvA.y;
        const float xB0 = xvB.x, xB1 = xvB.y;

        // -------- layer 1, both tiles, both branches, in B-frag layout --------
        float hdA[8], hoA[8], hdB[8], hoB[8];
        {
            float zdA[8], zoA[8], zdB[8], zoB[8];
            #pragma unroll
            for (int j = 0; j < 8; ++j) {
                zdA[j] = fmaf(xA1, w1d1[j], fmaf(xA0, w1d0[j], bd1[j]));
                zoA[j] = fmaf(xA1, w1o1[j], fmaf(xA0, w1o0[j], bo1[j]));
                zdB[j] = fmaf(xB1, w1d1[j], fmaf(xB0, w1d0[j], bd1[j]));
                zoB[j] = fmaf(xB1, w1o1[j], fmaf(xB0, w1o0[j], bo1[j]));
            }
            tanh4_pre(zdA[0], zdA[1], zdA[2], zdA[3], hdA[0], hdA[1], hdA[2], hdA[3]);
            tanh4_pre(zdB[0], zdB[1], zdB[2], zdB[3], hdB[0], hdB[1], hdB[2], hdB[3]);
            tanh4_pre(zdA[4], zdA[5], zdA[6], zdA[7], hdA[4], hdA[5], hdA[6], hdA[7]);
            tanh4_pre(zdB[4], zdB[5], zdB[6], zdB[7], hdB[4], hdB[5], hdB[6], hdB[7]);
            tanh4_pre(zoA[0], zoA[1], zoA[2], zoA[3], hoA[0], hoA[1], hoA[2], hoA[3]);
            tanh4_pre(zoB[0], zoB[1], zoB[2], zoB[3], hoB[0], hoB[1], hoB[2], hoB[3]);
            tanh4_pre(zoA[4], zoA[5], zoA[6], zoA[7], hoA[4], hoA[5], hoA[6], hoA[7]);
            tanh4_pre(zoB[4], zoB[5], zoB[6], zoB[7], hoB[4], hoB[5], hoB[6], hoB[7]);
        }
        bf16x8 bfdA, bfoA, bfdB, bfoB;
        #pragma unroll
        for (int j = 0; j < 8; ++j) {
            bfdA[j] = (__bf16)hdA[j];  bfoA[j] = (__bf16)hoA[j];   // v_cvt_pk_bf16_f32
            bfdB[j] = (__bf16)hdB[j];  bfoB[j] = (__bf16)hoB[j];
        }

        // -------- layer 2: 8 independent MFMAs (2 tiles x 2 j-tiles x 2 branches) --------
        f32x4 d0A = __builtin_amdgcn_mfma_f32_16x16x32_bf16(a_d2[0], bfdA, cd[0], 0, 0, 0);
        f32x4 d0B = __builtin_amdgcn_mfma_f32_16x16x32_bf16(a_d2[0], bfdB, cd[0], 0, 0, 0);
        f32x4 d1A = __builtin_amdgcn_mfma_f32_16x16x32_bf16(a_d2[1], bfdA, cd[1], 0, 0, 0);
        f32x4 d1B = __builtin_amdgcn_mfma_f32_16x16x32_bf16(a_d2[1], bfdB, cd[1], 0, 0, 0);
        f32x4 o0A = __builtin_amdgcn_mfma_f32_16x16x32_bf16(a_o2[0], bfoA, co[0], 0, 0, 0);
        f32x4 o0B = __builtin_amdgcn_mfma_f32_16x16x32_bf16(a_o2[0], bfoB, co[0], 0, 0, 0);
        f32x4 o1A = __builtin_amdgcn_mfma_f32_16x16x32_bf16(a_o2[1], bfoA, co[1], 0, 0, 0);
        f32x4 o1B = __builtin_amdgcn_mfma_f32_16x16x32_bf16(a_o2[1], bfoB, co[1], 0, 0, 0);

        // -------- layer 2 act (batched-rcp tanh), both tiles --------
        float h2dA[8], h2oA[8], h2dB[8], h2oB[8];
        tanh4_pre(d0A[0], d0A[1], d0A[2], d0A[3], h2dA[0], h2dA[1], h2dA[2], h2dA[3]);
        tanh4_pre(d0B[0], d0B[1], d0B[2], d0B[3], h2dB[0], h2dB[1], h2dB[2], h2dB[3]);
        tanh4_pre(d1A[0], d1A[1], d1A[2], d1A[3], h2dA[4], h2dA[5], h2dA[6], h2dA[7]);
        tanh4_pre(d1B[0], d1B[1], d1B[2], d1B[3], h2dB[4], h2dB[5], h2dB[6], h2dB[7]);
        tanh4_pre(o0A[0], o0A[1], o0A[2], o0A[3], h2oA[0], h2oA[1], h2oA[2], h2oA[3]);
        tanh4_pre(o0B[0], o0B[1], o0B[2], o0B[3], h2oB[0], h2oB[1], h2oB[2], h2oB[3]);
        tanh4_pre(o1A[0], o1A[1], o1A[2], o1A[3], h2oA[4], h2oA[5], h2oA[6], h2oA[7]);
        tanh4_pre(o1B[0], o1B[1], o1B[2], o1B[3], h2oB[4], h2oB[5], h2oB[6], h2oB[7]);

        // -------- layer 3 partials, both tiles --------
        float pd0A = 0.f, pd1A = 0.f, poA = 0.f, pd0B = 0.f, pd1B = 0.f, poB = 0.f;
        #pragma unroll
        for (int i = 0; i < 8; ++i) {
            pd0A = fmaf(h2dA[i], w3d0[i], pd0A);  pd0B = fmaf(h2dB[i], w3d0[i], pd0B);
            pd1A = fmaf(h2dA[i], w3d1[i], pd1A);  pd1B = fmaf(h2dB[i], w3d1[i], pd1B);
            poA  = fmaf(h2oA[i], w3o[i],  poA);   poB  = fmaf(h2oB[i], w3o[i],  poB);
        }
        // reduce across the 4 quads (same b16), all six values two-phase
        quad_sum6(pd0A, pd1A, poA, pd0B, pd1B, poB);

        // -------- epilogue, both tiles --------
        {
            float d30 = pd0A + bd3_0, d31 = pd1A + bd3_1, c = poA + bo3_0;
            float a = (fmaxf(d30, 0.f) + 0.001f) * xA0;
            float b = (fmaxf(d31, 0.f) + 0.001f) * xA1;
            float D0 = fmaf(a * a, xA0, a * c * xA1);
            float D1 = fmaf(a * c, xA0, fmaf(c, c, b * b) * xA1);
            if (quad == 0) o2v[2 * p * 16 + b16] = make_float2(D0, D1);
        }
        {
            float d30 = pd0B + bd3_0, d31 = pd1B + bd3_1, c = poB + bo3_0;
            float a = (fmaxf(d30, 0.f) + 0.001f) * xB0;
            float b = (fmaxf(d31, 0.f) + 0.001f) * xB1;
            float D0 = fmaf(a * a, xB0, a * c * xB1);
            float D1 = fmaf(a * c, xB0, fmaf(c, c, b * b) * xB1);
            int tB = 2 * p + 1;
            if (quad == 0 && tB < n_tiles) o2v[tB * 16 + b16] = make_float2(D0, D1);
        }

        xvA = xnA; xvB = xnB;
    }
}

extern "C" void kernel_launch(void* const* d_in, const int* in_sizes, int n_in,
                              void* d_out, int out_size, void* d_ws, size_t ws_size,
                              hipStream_t stream) {
    const float* x    = (const float*)d_in[0];
    const float* w_d1 = (const float*)d_in[1];
    const float* w_d2 = (const float*)d_in[2];
    const float* w_d3 = (const float*)d_in[3];
    const float* w_o1 = (const float*)d_in[4];
    const float* w_o2 = (const float*)d_in[5];
    const float* w_o3 = (const float*)d_in[6];
    const float* b_d1 = (const float*)d_in[7];
    const float* b_d2 = (const float*)d_in[8];
    const float* b_d3 = (const float*)d_in[9];
    const float* b_o1 = (const float*)d_in[10];
    const float* b_o2 = (const float*)d_in[11];
    const float* b_o3 = (const float*)d_in[12];
    float* out = (float*)d_out;

    int n = in_sizes[0] / 2;             // rows
    int n_tiles = n / 16;                // 16 rows per tile
    int n_pairs = (n_tiles + 1) / 2;     // 2 tiles per wave-iteration
    // grid 1024 blocks = 4096 waves -> 32768 pairs / 4096 = exactly 8 iters/wave.
    // TLP proven insensitive (R8); ILP=2 is the lever this round.
    int blocks_needed = (n_pairs + 3) / 4;
    int grid = blocks_needed < 1024 ? blocks_needed : 1024;
    damping_mfma<<<grid, 256, 0, stream>>>(
        x, w_d1, w_d2, w_d3, w_o1, w_o2, w_o3,
        b_d1, b_d2, b_d3, b_o1, b_o2, b_o3, out, n_tiles);
}